// Round 15
// baseline (50.086 us; speedup 1.0000x reference)
//
#include <hip/hip_runtime.h>

typedef float f32x2 __attribute__((ext_vector_type(2)));
typedef f32x2 c32;   // [0]=re, [1]=im
typedef _Float16 f16x8 __attribute__((ext_vector_type(8)));
typedef float f32x4 __attribute__((ext_vector_type(4)));

__device__ __forceinline__ c32 mkc(float x, float y) { c32 r; r[0] = x; r[1] = y; return r; }

__device__ __forceinline__ c32 cmul(c32 a, c32 b) {
    c32 r;
    asm("v_pk_mul_f32 %0, %1, %2 op_sel:[0,0] op_sel_hi:[0,1]\n\t"
        "v_pk_fma_f32 %0, %1, %2, %0 op_sel:[1,1,0] op_sel_hi:[1,0,1] neg_lo:[1,0,0]"
        : "=&v"(r) : "v"(a), "v"(b));
    return r;
}
__device__ __forceinline__ c32 cmad(c32 a, c32 b, c32 acc) {
    asm("v_pk_fma_f32 %0, %1, %2, %0 op_sel:[0,0,0] op_sel_hi:[0,1,1]\n\t"
        "v_pk_fma_f32 %0, %1, %2, %0 op_sel:[1,1,0] op_sel_hi:[1,0,1] neg_lo:[1,0,0]"
        : "+v"(acc) : "v"(a), "v"(b));
    return acc;
}

// ---------------- gate-matrix build (verified) -----------------------------

__device__ __forceinline__ void mk_u3(float th, float ph, float la, c32 U[2][2]) {
    float ct = __cosf(0.5f * th), st = __sinf(0.5f * th);
    U[0][0] = mkc(ct, 0.f);
    U[0][1] = mkc(-__cosf(la) * st, -__sinf(la) * st);
    U[1][0] = mkc(__cosf(ph) * st, __sinf(ph) * st);
    U[1][1] = mkc(__cosf(ph + la) * ct, __sinf(ph + la) * ct);
}

__device__ __forceinline__ void lmul_kron(const c32 A[2][2], const c32 B[2][2], c32 m[4]) {
    c32 t[4];
#pragma unroll
    for (int r = 0; r < 4; ++r) {
        c32 acc = mkc(0.f, 0.f);
#pragma unroll
        for (int k = 0; k < 4; ++k)
            acc = cmad(cmul(A[r >> 1][k >> 1], B[r & 1][k & 1]), m[k], acc);
        t[r] = acc;
    }
#pragma unroll
    for (int r = 0; r < 4; ++r) m[r] = t[r];
}

__device__ void build_col(const float* __restrict__ w, int t, c32* gml) {
    const int g = t >> 2, c = t & 3;
    const float* p = w + g * 15;
    const int c0 = c >> 1, c1 = c & 1;
    c32 A[2][2], B[2][2], m[4], tmp;

    mk_u3(p[0], p[1], p[2], A);
    mk_u3(p[3], p[4], p[5], B);
#pragma unroll
    for (int r = 0; r < 4; ++r) m[r] = cmul(A[r >> 1][c0], B[r & 1][c1]);
    tmp = m[2]; m[2] = m[3]; m[3] = tmp;                 // CNOT(w0->w1)
    {
        float cc = __cosf(0.5f * p[6]), s = __sinf(0.5f * p[6]);
        A[0][0] = mkc(cc, 0.f); A[0][1] = mkc(-s, 0.f);
        A[1][0] = mkc(s, 0.f);  A[1][1] = mkc(cc, 0.f);
        float cz = __cosf(0.5f * p[7]), sz = __sinf(0.5f * p[7]);
        B[0][0] = mkc(cz, -sz); B[0][1] = mkc(0.f, 0.f);
        B[1][0] = mkc(0.f, 0.f); B[1][1] = mkc(cz, sz);
        lmul_kron(A, B, m);
    }
    tmp = m[1]; m[1] = m[3]; m[3] = tmp;                 // CNOT(w1->w0)
    {
        float cc = __cosf(0.5f * p[8]), s = __sinf(0.5f * p[8]);
        A[0][0] = mkc(cc, 0.f); A[0][1] = mkc(-s, 0.f);
        A[1][0] = mkc(s, 0.f);  A[1][1] = mkc(cc, 0.f);
        B[0][0] = mkc(1.f, 0.f); B[0][1] = mkc(0.f, 0.f);
        B[1][0] = mkc(0.f, 0.f); B[1][1] = mkc(1.f, 0.f);
        lmul_kron(A, B, m);
    }
    tmp = m[2]; m[2] = m[3]; m[3] = tmp;                 // CNOT(w0->w1)
    mk_u3(p[9], p[10], p[11], A);
    mk_u3(p[12], p[13], p[14], B);
    lmul_kron(A, B, m);
#pragma unroll
    for (int r = 0; r < 4; ++r) gml[g * 16 + r * 4 + c] = m[r];
}

// ---- 4x4 gate applied to a 16-vector on local bits (A,B) — R4-verified ----

constexpr int freePos(int A, int B, int k) {
    int cnt = 0;
    for (int p = 0; p < 4; ++p)
        if (p != A && p != B) { if (cnt == k) return p; ++cnt; }
    return -1;
}

template<int A, int B>
__device__ __forceinline__ void gate16(const c32 m[16], c32 s[16]) {
    constexpr int C0 = freePos(A, B, 0);
    constexpr int C1 = freePos(A, B, 1);
#pragma unroll
    for (int q = 0; q < 4; ++q) {
        const int base = ((q & 1) << C0) | (((q >> 1) & 1) << C1);
        const int i00 = base, i01 = base | (1 << B), i10 = base | (1 << A),
                  i11 = base | (1 << A) | (1 << B);
        c32 a0 = s[i00], a1 = s[i01], a2 = s[i10], a3 = s[i11];
        c32 r0 = cmul(m[0],  a0); r0 = cmad(m[1],  a1, r0); r0 = cmad(m[2],  a2, r0); r0 = cmad(m[3],  a3, r0);
        c32 r1 = cmul(m[4],  a0); r1 = cmad(m[5],  a1, r1); r1 = cmad(m[6],  a2, r1); r1 = cmad(m[7],  a3, r1);
        c32 r2 = cmul(m[8],  a0); r2 = cmad(m[9],  a1, r2); r2 = cmad(m[10], a2, r2); r2 = cmad(m[11], a3, r2);
        c32 r3 = cmul(m[12], a0); r3 = cmad(m[13], a1, r3); r3 = cmad(m[14], a2, r3); r3 = cmad(m[15], a3, r3);
        s[i00] = r0; s[i01] = r1; s[i10] = r2; s[i11] = r3;
    }
}

// ---------------- K1: 16x16 window matrices --------------------------------
// Window locals (verified R4/R12 mapping):
//  E (=A=B struct): gates (3,2),(1,0),(2,1) with layer mat
//  C: gates (2,1),(0,3)
//  D: mats2,3: (2,1),(0,3),(3,2),(1,0) each; mat4: (2,0)
// W16 layout in ws: [0]=E16_1 [1]=C16_1 [2]=E16_2 [3]=C16_2 [4]=D16 (row-major i*16+col)

__global__ __launch_bounds__(256) void build_kernel(const float* __restrict__ w,
                                                    c32* __restrict__ ws) {
    __shared__ c32 GML[80];
    const int t = threadIdx.x;
    if (t < 20) build_col(w, t, GML);
    __syncthreads();
    if (t < 80) {
        const int wm = t >> 4, col = t & 15;
        c32 v[16];
#pragma unroll
        for (int r = 0; r < 16; ++r) v[r] = mkc(r == col ? 1.f : 0.f, 0.f);
        if (wm == 0 || wm == 2) {
            const c32* mm = GML + (wm == 0 ? 0 : 1) * 16;
            gate16<3, 2>(mm, v); gate16<1, 0>(mm, v); gate16<2, 1>(mm, v);
        } else if (wm == 1 || wm == 3) {
            const c32* mm = GML + (wm == 1 ? 0 : 1) * 16;
            gate16<2, 1>(mm, v); gate16<0, 3>(mm, v);
        } else {
            const c32* m2 = GML + 2 * 16;
            gate16<2, 1>(m2, v); gate16<0, 3>(m2, v); gate16<3, 2>(m2, v); gate16<1, 0>(m2, v);
            const c32* m3 = GML + 3 * 16;
            gate16<2, 1>(m3, v); gate16<0, 3>(m3, v); gate16<3, 2>(m3, v); gate16<1, 0>(m3, v);
            const c32* m4 = GML + 4 * 16;
            gate16<2, 0>(m4, v);
        }
#pragma unroll
        for (int r = 0; r < 16; ++r) ws[wm * 256 + r * 16 + col] = v[r];
    }
}

// ---------------- K2: dense pass1 and E = D̄·pass2 -------------------------
// pass[i,j] = sum_m C16[c(i),m] * E16[k>>4, j>>4]*E16[k&15, j&15], k = cRest(i)|cScat(m)
// c(i): bits {7,4,3,0}; cRest mask 0x66. d(i): bits {7,5,3,1}; dRest mask 0x55.

__device__ __forceinline__ int cScat(int m) {
    return ((m & 8) << 4) | ((m & 4) << 2) | ((m & 2) << 2) | (m & 1);
}
__device__ __forceinline__ int dScat(int m) {
    return ((m & 8) << 4) | ((m & 4) << 3) | ((m & 2) << 2) | ((m & 1) << 1);
}

__global__ __launch_bounds__(256) void pass_kernel(const c32* __restrict__ ws,
                                                   c32* __restrict__ pass1cm,
                                                   c32* __restrict__ Ecm) {
    __shared__ c32 E16L[256], C16L[256], D16L[256], kcol[256], pcol[256];
    const int tid = threadIdx.x;
    const int p = blockIdx.x >> 6;           // 0: pass1, 1: pass2(+D-fold)
    const int jbase = (blockIdx.x & 63) * 4;
    E16L[tid] = ws[(p ? 2 : 0) * 256 + tid];
    C16L[tid] = ws[(p ? 3 : 1) * 256 + tid];
    D16L[tid] = ws[4 * 256 + tid];
    __syncthreads();

    const int i = tid;
    const int ci = (((i >> 7) & 1) << 3) | (((i >> 4) & 1) << 2) | (((i >> 3) & 1) << 1) | (i & 1);
    const int crest = i & 0x66;
    const int di = (((i >> 7) & 1) << 3) | (((i >> 5) & 1) << 2) | (((i >> 3) & 1) << 1) | ((i >> 1) & 1);
    const int drest = i & 0x55;

    for (int jj = 0; jj < 4; ++jj) {
        const int j = jbase + jj;
        __syncthreads();
        kcol[tid] = cmul(E16L[(tid >> 4) * 16 + (j >> 4)], E16L[(tid & 15) * 16 + (j & 15)]);
        __syncthreads();
        c32 val = mkc(0.f, 0.f);
#pragma unroll
        for (int m = 0; m < 16; ++m)
            val = cmad(C16L[ci * 16 + m], kcol[crest | cScat(m)], val);
        if (p == 0) {
            pass1cm[j * 256 + i] = val;
        } else {
            pcol[i] = val;
            __syncthreads();
            c32 e = mkc(0.f, 0.f);
#pragma unroll
            for (int m = 0; m < 16; ++m)
                e = cmad(D16L[di * 16 + m], pcol[drest | dScat(m)], e);
            Ecm[j * 256 + i] = e;   // E column j contiguous
        }
    }
}

// ---------------- K3: U = E · pass1, cast fp16 -----------------------------
// U16 row-major [512][256]: rows 0-255 = Re, 256-511 = Im (R13-verified layout)

__global__ __launch_bounds__(256) void combine_kernel(const c32* __restrict__ pass1cm,
                                                      const c32* __restrict__ Ecm,
                                                      _Float16* __restrict__ U16) {
    __shared__ c32 p0[256], p1[256];
    const int tid = threadIdx.x;
    const int j0 = blockIdx.x * 2;
    p0[tid] = pass1cm[j0 * 256 + tid];
    p1[tid] = pass1cm[(j0 + 1) * 256 + tid];
    __syncthreads();
    c32 a0 = mkc(0.f, 0.f), a1 = mkc(0.f, 0.f);
#pragma unroll 8
    for (int k = 0; k < 256; ++k) {
        c32 e = Ecm[k * 256 + tid];   // coalesced across lanes
        a0 = cmad(e, p0[k], a0);
        a1 = cmad(e, p1[k], a1);
    }
    U16[(size_t)tid * 256 + j0]           = (_Float16)a0[0];
    U16[(size_t)(tid + 256) * 256 + j0]   = (_Float16)a0[1];
    U16[(size_t)tid * 256 + j0 + 1]       = (_Float16)a1[0];
    U16[(size_t)(tid + 256) * 256 + j0 + 1] = (_Float16)a1[1];
}

// ---------------- K4: batch GEMM + expectations (R13-verified, verbatim) ---

__global__ __launch_bounds__(256) void gemm_expect_kernel(const float* __restrict__ x,
                                                          const _Float16* __restrict__ U16,
                                                          float* __restrict__ out) {
    __shared__ _Float16 Bl[32][264];
    __shared__ float nn[32];
    __shared__ float red[4][2][16][9];
    const int tid = threadIdx.x;
    const int wave = tid >> 6, lane = tid & 63;
    const int bs = blockIdx.x * 32;

    {
        const int n = tid >> 3, sub = tid & 7;
        const float4* xr = reinterpret_cast<const float4*>(x + (size_t)(bs + n) * 256 + sub * 32);
        float ssq = 0.f;
#pragma unroll
        for (int q = 0; q < 8; ++q) {
            float4 v = xr[q];
            ssq = fmaf(v.x, v.x, fmaf(v.y, v.y, fmaf(v.z, v.z, fmaf(v.w, v.w, ssq))));
            const int k0 = sub * 32 + q * 4;
            Bl[n][k0 + 0] = (_Float16)v.x;
            Bl[n][k0 + 1] = (_Float16)v.y;
            Bl[n][k0 + 2] = (_Float16)v.z;
            Bl[n][k0 + 3] = (_Float16)v.w;
        }
#pragma unroll
        for (int o = 4; o; o >>= 1) ssq += __shfl_xor(ssq, o, 64);
        if (sub == 0) nn[n] = ssq;
    }
    __syncthreads();

    f32x4 acc[2][4][2];
#pragma unroll
    for (int ri = 0; ri < 2; ++ri)
#pragma unroll
        for (int a = 0; a < 4; ++a)
#pragma unroll
            for (int nt = 0; nt < 2; ++nt) acc[ri][a][nt] = (f32x4){0.f, 0.f, 0.f, 0.f};

    const int ml = lane & 15, g = lane >> 4;
    const _Float16* Abase[2][4];
#pragma unroll
    for (int ri = 0; ri < 2; ++ri)
#pragma unroll
        for (int a = 0; a < 4; ++a)
            Abase[ri][a] = U16 + (size_t)(64 * wave + 16 * a + 256 * ri + ml) * 256 + g * 8;

#pragma unroll
    for (int kt = 0; kt < 8; ++kt) {
        f16x8 bf[2];
#pragma unroll
        for (int nt = 0; nt < 2; ++nt)
            bf[nt] = *reinterpret_cast<const f16x8*>(&Bl[nt * 16 + ml][kt * 32 + g * 8]);
#pragma unroll
        for (int ri = 0; ri < 2; ++ri)
#pragma unroll
            for (int a = 0; a < 4; ++a) {
                f16x8 af = *reinterpret_cast<const f16x8*>(Abase[ri][a] + kt * 32);
#pragma unroll
                for (int nt = 0; nt < 2; ++nt)
                    acc[ri][a][nt] = __builtin_amdgcn_mfma_f32_16x16x32_f16(af, bf[nt], acc[ri][a][nt], 0, 0, 0);
            }
    }

#pragma unroll
    for (int nt = 0; nt < 2; ++nt) {
        float E[9];
#pragma unroll
        for (int m = 0; m < 9; ++m) E[m] = 0.f;
#pragma unroll
        for (int a = 0; a < 4; ++a) {
#pragma unroll
            for (int r = 0; r < 4; ++r) {
                float re = acc[0][a][nt][r], im = acc[1][a][nt][r];
                float pr = re * re + im * im;
                E[2] += (a & 2) ? -pr : pr;
                E[5] += (r & 2) ? -pr : pr;
                E[8] += ((a ^ r) & 2) ? -pr : pr;
                if (a < 2) {
                    float pre = acc[0][a + 2][nt][r], pim = acc[1][a + 2][nt][r];
                    E[0] += 2.f * (re * pre + im * pim);
                    E[1] += 2.f * (re * pim - im * pre);
                    float dre = acc[0][a + 2][nt][r ^ 2], dim = acc[1][a + 2][nt][r ^ 2];
                    float dr = re * dre + im * dim;
                    E[6] += 2.f * dr;
                    E[7] += (r & 2) ? 2.f * dr : -2.f * dr;
                }
                if (!(r & 2)) {
                    float qre = acc[0][a][nt][r + 2], qim = acc[1][a][nt][r + 2];
                    E[3] += 2.f * (re * qre + im * qim);
                    E[4] += 2.f * (re * qim - im * qre);
                }
            }
        }
#pragma unroll
        for (int m = 0; m < 9; ++m) {
            E[m] += __shfl_xor(E[m], 16, 64);
            E[m] += __shfl_xor(E[m], 32, 64);
            if (lane < 16) red[wave][nt][lane][m] = E[m];
        }
    }
    __syncthreads();

    if (tid < 32) {
        const int nt = tid >> 4, nc = tid & 15;
        const float innv = 1.0f / nn[tid];
#pragma unroll
        for (int m = 0; m < 9; ++m) {
            float e = red[0][nt][nc][m] + red[1][nt][nc][m] +
                      red[2][nt][nc][m] + red[3][nt][nc][m];
            out[(size_t)(bs + tid) * 9 + m] = e * innv;
        }
    }
}

extern "C" void kernel_launch(void* const* d_in, const int* in_sizes, int n_in,
                              void* d_out, int out_size, void* d_ws, size_t ws_size,
                              hipStream_t stream) {
    const float* x = (const float*)d_in[0];
    const float* w = (const float*)d_in[1];
    float* out = (float*)d_out;

    c32* ws0      = (c32*)d_ws;
    c32* pass1cm  = ws0 + 2048;
    c32* Ecm      = ws0 + 2048 + 65536;
    _Float16* U16 = (_Float16*)(ws0 + 2048 + 2 * 65536);

    hipLaunchKernelGGL(build_kernel,   dim3(1),   dim3(256), 0, stream, w, ws0);
    hipLaunchKernelGGL(pass_kernel,    dim3(128), dim3(256), 0, stream, ws0, pass1cm, Ecm);
    hipLaunchKernelGGL(combine_kernel, dim3(128), dim3(256), 0, stream, pass1cm, Ecm, U16);

    const int batch = in_sizes[0] / 256;     // 8192
    hipLaunchKernelGGL(gemm_expect_kernel, dim3(batch / 32), dim3(256), 0, stream, x, U16, out);
}